// Round 4
// baseline (509.286 us; speedup 1.0000x reference)
//
#include <hip/hip_runtime.h>
#include <hip/hip_bf16.h>

#define LSEQ   2048
#define DK     64
#define NH     16
#define BS     2
#define DMODEL 1024
#define BH     (BS*NH)    // 32
#define MTOT   (BS*LSEQ)  // 4096

typedef __attribute__((ext_vector_type(8))) short bf16x8;
typedef __attribute__((ext_vector_type(4))) float f32x4;

#define MFMA16(a,b,c) __builtin_amdgcn_mfma_f32_16x16x32_bf16((a),(b),(c),0,0,0)
#define GLD_LDS(g,l) __builtin_amdgcn_global_load_lds((const __attribute__((address_space(1))) void*)(g), (__attribute__((address_space(3))) void*)(l), 16, 0, 0)

__device__ __forceinline__ short f2bs(float f) {
  union { __hip_bfloat16 h; short s; } u; u.h = __float2bfloat16(f); return u.s;
}
__device__ __forceinline__ float b2f(unsigned short s) {
  union { unsigned u; float f; } v; v.u = ((unsigned)s) << 16; return v.f;
}
// cheap round-half-up bf16 (inputs guaranteed finite)
__device__ __forceinline__ unsigned short f2bs_c(float f) {
  union { float f; unsigned u; } v; v.f = f;
  return (unsigned short)((v.u + 0x8000u) >> 16);
}
__device__ __forceinline__ unsigned pk2c(float lo, float hi) {
  union { float f; unsigned u; } a, b; a.f = lo; b.f = hi;
  return ((a.u + 0x8000u) >> 16) | ((b.u + 0x8000u) & 0xffff0000u);
}
__device__ __forceinline__ unsigned pk2(float lo, float hi) {
  return (unsigned)(unsigned short)f2bs(lo) | (((unsigned)(unsigned short)f2bs(hi)) << 16);
}

// ---------------- f32 -> bf16 flat convert (vectorized) ----------------
__global__ __launch_bounds__(256) void cvt_bf16_k(const float* __restrict__ in,
                                                  short* __restrict__ out, int n8) {
  for (int i = blockIdx.x * blockDim.x + threadIdx.x; i < n8; i += gridDim.x * blockDim.x) {
    const float4* p = (const float4*)in + (size_t)i * 2;
    float4 a = p[0], b = p[1];
    uint4 o;
    o.x = pk2(a.x, a.y); o.y = pk2(a.z, a.w);
    o.z = pk2(b.x, b.y); o.w = pk2(b.z, b.w);
    ((uint4*)out)[i] = o;
  }
}

// ---------------- f32 [K][N] -> bf16 transposed [N][K] ----------------
__global__ __launch_bounds__(256) void cvt_tr_k(const float* __restrict__ W,
                                                short* __restrict__ Wt,
                                                int Krows, int Ncols) {
  __shared__ float tile[32][33];
  int n0 = blockIdx.x * 32, k0 = blockIdx.y * 32;
  int t = threadIdx.x;
#pragma unroll
  for (int i = 0; i < 4; ++i) {
    int idx = t + i * 256; int r = idx >> 5, c = idx & 31;
    tile[r][c] = W[(size_t)(k0 + r) * Ncols + n0 + c];
  }
  __syncthreads();
#pragma unroll
  for (int i = 0; i < 4; ++i) {
    int idx = t + i * 256; int r = idx >> 5, c = idx & 31;
    Wt[(size_t)(n0 + r) * Krows + k0 + c] = f2bs(tile[c][r]);
  }
}

// ---------------- 128x128-tile bf16 GEMM, K=1024 ----------------
__global__ __launch_bounds__(256) void gemm128_k(
    const short* __restrict__ A, const short* __restrict__ Bt,
    const float* __restrict__ bias, int mode,
    float* __restrict__ outF,
    short* __restrict__ Qb, short* __restrict__ Kb, short* __restrict__ VTb) {
  __shared__ short As[128 * 64];
  __shared__ short Bs[128 * 64];
  int tid = threadIdx.x, w = tid >> 6, ln = tid & 63, lg = ln >> 4, lr = ln & 15;
  int m0 = blockIdx.x * 128, n0 = blockIdx.y * 128;
  int wr = w >> 1, wc = w & 1;
  f32x4 acc[4][4] = {};

  for (int k0 = 0; k0 < 1024; k0 += 64) {
    __syncthreads();
#pragma unroll
    for (int i = 0; i < 4; ++i) {
      int cb = w * 64 + i * 256;
      int c = cb + ln;
      GLD_LDS(A  + (size_t)(m0 + (c >> 3)) * 1024 + k0 + (c & 7) * 8, &As[cb * 8]);
      GLD_LDS(Bt + (size_t)(n0 + (c >> 3)) * 1024 + k0 + (c & 7) * 8, &Bs[cb * 8]);
    }
    __syncthreads();
#pragma unroll
    for (int kh = 0; kh < 2; ++kh) {
      bf16x8 af[4], bfr[4];
#pragma unroll
      for (int mi = 0; mi < 4; ++mi)
        af[mi] = *(const bf16x8*)&As[(wr * 64 + mi * 16 + lr) * 64 + kh * 32 + lg * 8];
#pragma unroll
      for (int ni = 0; ni < 4; ++ni)
        bfr[ni] = *(const bf16x8*)&Bs[(wc * 64 + ni * 16 + lr) * 64 + kh * 32 + lg * 8];
#pragma unroll
      for (int mi = 0; mi < 4; ++mi)
#pragma unroll
        for (int ni = 0; ni < 4; ++ni)
          acc[mi][ni] = MFMA16(af[mi], bfr[ni], acc[mi][ni]);
    }
  }

#pragma unroll
  for (int ni = 0; ni < 4; ++ni) {
    int n = n0 + wc * 64 + ni * 16 + lr;
    float bv = bias[n];
    int part = n >> 10, cc = n & 1023, h = cc >> 6, dd = cc & 63;
#pragma unroll
    for (int mi = 0; mi < 4; ++mi) {
      int mbase = m0 + wr * 64 + mi * 16 + 4 * lg;
      float vv[4];
#pragma unroll
      for (int r = 0; r < 4; ++r) vv[r] = acc[mi][ni][r] + bv;
      if (mode == 1) {
#pragma unroll
        for (int r = 0; r < 4; ++r) outF[(size_t)(mbase + r) * 1024 + n] = vv[r];
      } else if (part == 2) {
        int b = mbase >> 11, tok = mbase & 2047, bh = b * NH + h;
        uint2 pk; pk.x = pk2c(vv[0], vv[1]); pk.y = pk2c(vv[2], vv[3]);
        *(uint2*)&VTb[((size_t)bh * DK + dd) * LSEQ + tok] = pk;
      } else {
        short* dst = (part == 0) ? Qb : Kb;
#pragma unroll
        for (int r = 0; r < 4; ++r) {
          int m = mbase + r;
          int b = m >> 11, tok = m & 2047, bh = b * NH + h;
          dst[((size_t)bh * LSEQ + tok) * DK + dd] = (short)f2bs_c(vv[r]);
        }
      }
    }
  }
}

// ---------------- per-row squared norms ----------------
__global__ __launch_bounds__(256) void norms_k(
    const short* __restrict__ Qm, const short* __restrict__ Qs,
    const short* __restrict__ Km, const short* __restrict__ Ks,
    float* __restrict__ sqq, float* __restrict__ sqk) {
  int id = blockIdx.x * 256 + threadIdx.x;  // 0..131071
  int row = id & 65535;
  const short* p1 = (id < 65536) ? Qm : Km;
  const short* p2 = (id < 65536) ? Qs : Ks;
  float* outp = (id < 65536) ? sqq : sqk;
  const uint4* a = (const uint4*)(p1 + (size_t)row * DK);
  const uint4* b = (const uint4*)(p2 + (size_t)row * DK);
  float s = 0.f;
#pragma unroll
  for (int i = 0; i < 8; ++i) {
    uint4 x = a[i], y = b[i];
    unsigned vx[4] = {x.x, x.y, x.z, x.w};
    unsigned vy[4] = {y.x, y.y, y.z, y.w};
#pragma unroll
    for (int j = 0; j < 4; ++j) {
      float l1 = b2f((unsigned short)(vx[j] & 0xffff)), h1 = b2f((unsigned short)(vx[j] >> 16));
      float l2 = b2f((unsigned short)(vy[j] & 0xffff)), h2 = b2f((unsigned short)(vy[j] >> 16));
      s += l1 * l1 + h1 * h1 + l2 * l2 + h2 * h2;
    }
  }
  outp[row] = s;
}

// ---------------- fused Wasserstein attention ----------------
// grid (L/128, BH); 512 threads = 8 waves.
// Wave w = (qgrp = w&3, khalf = w>>2): owns 32 q-rows [q0+32*qgrp, +32)
// and k-half [khalf*32, khalf*32+32) of each 64-k tile.
// Swapped QK^T (S[k][q]); P is wave-private (each wave reads only the
// P columns it wrote). Partial O/rowsum combined across the wave pair
// at kernel end through LDS scratch.
__global__ __launch_bounds__(512, 4) void attn_k(
    const short* __restrict__ Qm, const short* __restrict__ Km, const short* __restrict__ VmT,
    const short* __restrict__ Qs, const short* __restrict__ Ks, const short* __restrict__ VsT,
    const float* __restrict__ sqq, const float* __restrict__ sqk,
    short* __restrict__ Om, short* __restrict__ Os) {
  int bh = blockIdx.y;
  int q0 = blockIdx.x * 128;
  int tid = threadIdx.x, w = tid >> 6, ln = tid & 63, lg = ln >> 4, lr = ln & 15;
  int qgrp = w & 3, kh2 = w >> 2;

  __shared__ __align__(16) char pool[55296];
  short* Km_t = (short*)pool;             // [64][72]
  short* Ks_t = (short*)(pool + 9216);    // [64][72]
  short* Vt_t = (short*)(pool + 18432);   // [128][72]
  short* P_t  = (short*)(pool + 36864);   // [4][32][72]

  const size_t bhQ = (size_t)bh * LSEQ * DK;

  // Q fragments (MFMA B operand: col=lr=q, k=lg*8+j)
  bf16x8 qm[2][2], qs[2][2];
  float sqQ[2];
#pragma unroll
  for (int qg = 0; qg < 2; ++qg) {
    int q = q0 + qgrp * 32 + qg * 16 + lr;
    const short* qpm = Qm + bhQ + (size_t)q * DK;
    const short* qps = Qs + bhQ + (size_t)q * DK;
    qm[qg][0] = *(const bf16x8*)(qpm + lg * 8);
    qm[qg][1] = *(const bf16x8*)(qpm + 32 + lg * 8);
    qs[qg][0] = *(const bf16x8*)(qps + lg * 8);
    qs[qg][1] = *(const bf16x8*)(qps + 32 + lg * 8);
    sqQ[qg] = sqq[(size_t)bh * LSEQ + q];
  }
  const float* sqkp = sqk + (size_t)bh * LSEQ;

  // staging: 512 threads; K tiles 1 int4 each, V tile 2 int4 each.
  // Diagonal slot rotation: LDS bank granule == (tid&7) -> conflict-free writes.
  int sr = tid >> 3;
  int sc = ((tid & 7) - sr) & 7;
  const short* kmsrc  = Km  + bhQ + (size_t)sr * DK + sc * 8;
  const short* kssrc  = Ks  + bhQ + (size_t)sr * DK + sc * 8;
  const short* vm_src = VmT + ((size_t)bh * DK + sr) * LSEQ + sc * 8;
  const short* vs_src = VsT + ((size_t)bh * DK + sr) * LSEQ + sc * 8;

  int4 rKm = *(const int4*)kmsrc;
  int4 rKs = *(const int4*)kssrc;
  int4 rV0 = *(const int4*)vm_src;
  int4 rV1 = *(const int4*)vs_src;

  f32x4 acc0[8] = {}, acc1[8] = {};
  float prs[2] = {0.f, 0.f};

  for (int kt = 0; kt < LSEQ / 64; ++kt) {
    int k0 = kt * 64;
    __syncthreads();   // all reads of previous tile done
    *(int4*)&Km_t[sr * 72 + sc * 8] = rKm;
    *(int4*)&Ks_t[sr * 72 + sc * 8] = rKs;
    *(int4*)&Vt_t[sr * 72 + sc * 8] = rV0;
    *(int4*)&Vt_t[(sr + 64) * 72 + sc * 8] = rV1;
    __syncthreads();   // staged tile visible

    // prefetch next tile into registers (latency hides under compute)
    {
      int k0n = (kt < LSEQ / 64 - 1) ? (k0 + 64) : k0;
      rKm = *(const int4*)(kmsrc + (size_t)k0n * DK);
      rKs = *(const int4*)(kssrc + (size_t)k0n * DK);
      rV0 = *(const int4*)(vm_src + k0n);
      rV1 = *(const int4*)(vs_src + k0n);
    }

    // QK^T for this wave's k-half (2 jt sub-tiles), both q-groups
#pragma unroll
    for (int jj = 0; jj < 2; ++jj) {
      int jt = kh2 * 2 + jj;
      const short* kmr = &Km_t[(jt * 16 + lr) * 72];
      const short* ksr = &Ks_t[(jt * 16 + lr) * 72];
      bf16x8 bm0 = *(const bf16x8*)(kmr + lg * 8);
      bf16x8 bm1 = *(const bf16x8*)(kmr + 32 + lg * 8);
      bf16x8 bs0 = *(const bf16x8*)(ksr + lg * 8);
      bf16x8 bs1 = *(const bf16x8*)(ksr + 32 + lg * 8);
      f32x4 rsk = *(const f32x4*)&sqkp[k0 + jt * 16 + 4 * lg];
#pragma unroll
      for (int qg = 0; qg < 2; ++qg) {
        f32x4 s = {0.f, 0.f, 0.f, 0.f};
        s = MFMA16(bm0, qm[qg][0], s);
        s = MFMA16(bm1, qm[qg][1], s);
        s = MFMA16(bs0, qs[qg][0], s);
        s = MFMA16(bs1, qs[qg][1], s);
        float p[4];
#pragma unroll
        for (int r = 0; r < 4; ++r) {
          float w2 = fmaf(-2.f, s[r], rsk[r] + sqQ[qg]);
          float wd = sqrtf(fmaxf(w2, 0.f));
          float sim = __expf(-wd);
          p[r] = __expf(sim);
        }
        prs[qg] += (p[0] + p[1]) + (p[2] + p[3]);
        uint2 pk; pk.x = pk2c(p[0], p[1]); pk.y = pk2c(p[2], p[3]);
        *(uint2*)&P_t[(qgrp * 32 + qg * 16 + lr) * 72 + jt * 16 + 4 * lg] = pk;
      }
    }

    // PV over this wave's k-half only: O[v][q] += V·P
    {
      bf16x8 pa0 = *(const bf16x8*)&P_t[(qgrp * 32 + lr) * 72 + kh2 * 32 + lg * 8];
      bf16x8 pa1 = *(const bf16x8*)&P_t[(qgrp * 32 + 16 + lr) * 72 + kh2 * 32 + lg * 8];
#pragma unroll
      for (int vt = 0; vt < 8; ++vt) {
        bf16x8 vb = *(const bf16x8*)&Vt_t[(vt * 16 + lr) * 72 + kh2 * 32 + lg * 8];
        acc0[vt] = MFMA16(vb, pa0, acc0[vt]);
        acc1[vt] = MFMA16(vb, pa1, acc1[vt]);
      }
    }
  }

  // reduce prs across the 4 lg groups (lanes sharing lr)
#pragma unroll
  for (int qg = 0; qg < 2; ++qg) {
    float v = prs[qg];
    v += __shfl_xor(v, 16);
    v += __shfl_xor(v, 32);
    prs[qg] = v;
  }

  // combine partial O / rowsums across the wave pair (khalf 0 <- khalf 1)
  float* scr  = (float*)pool;             // [4 qgrp][8 vt][64 ln] f32x4 = 32 KB
  float* scrP = (float*)(pool + 32768);   // [4 qgrp][64 ln] floats = 1 KB
  int b = bh >> 4, h = bh & 15;

#pragma unroll
  for (int qg = 0; qg < 2; ++qg) {
    __syncthreads();
    if (kh2 == 1) {
      const f32x4* a = qg ? acc1 : acc0;
#pragma unroll
      for (int vt = 0; vt < 8; ++vt)
        *(f32x4*)&scr[qgrp * 2048 + (vt * 64 + ln) * 4] = a[vt];
      scrP[qgrp * 64 + ln] = prs[qg];
    }
    __syncthreads();
    if (kh2 == 0) {
      const f32x4* a = qg ? acc1 : acc0;
      float inv = 1.f / (prs[qg] + scrP[qgrp * 64 + ln]);
      int tok = q0 + qgrp * 32 + qg * 16 + lr;
      size_t orow = ((size_t)(b * LSEQ + tok)) * DMODEL + h * DK;
#pragma unroll
      for (int vt = 0; vt < 8; ++vt) {
        f32x4 o = a[vt] + *(const f32x4*)&scr[qgrp * 2048 + (vt * 64 + ln) * 4];
        short* obuf = (vt < 4) ? Om : Os;
        int vd = (vt & 3) * 16 + 4 * lg;
        uint2 pk; pk.x = pk2c(o[0] * inv, o[1] * inv);
        pk.y = pk2c(o[2] * inv, o[3] * inv);
        *(uint2*)(obuf + orow + vd) = pk;
      }
    }
  }
}

extern "C" void kernel_launch(void* const* d_in, const int* in_sizes, int n_in,
                              void* d_out, int out_size, void* d_ws, size_t ws_size,
                              hipStream_t stream) {
  const float* mu    = (const float*)d_in[0];
  const float* sigma = (const float*)d_in[1];
  const float* Wqm   = (const float*)d_in[2];
  const float* bqm   = (const float*)d_in[3];
  const float* Wqs   = (const float*)d_in[4];
  const float* bqs   = (const float*)d_in[5];
  const float* Wo    = (const float*)d_in[6];
  const float* bo    = (const float*)d_in[7];
  float* out = (float*)d_out;
  char* ws = (char*)d_ws;
  const size_t MB = 1u << 20;

  short* Amu   = (short*)(ws + 0);        // 8MB, reused as Om
  short* Asg   = (short*)(ws + 8 * MB);   // 8MB, reused as Os (contiguous with Om)
  short* Wqm_t = (short*)(ws + 16 * MB);  // 6MB
  short* Wqs_t = (short*)(ws + 22 * MB);  // 6MB
  short* Wo_t  = (short*)(ws + 28 * MB);  // 2MB
  short* Qm    = (short*)(ws + 30 * MB);  // 8MB each below
  short* Km    = (short*)(ws + 38 * MB);
  short* VmT   = (short*)(ws + 46 * MB);
  short* Qs    = (short*)(ws + 54 * MB);
  short* Ks    = (short*)(ws + 62 * MB);
  short* VsT   = (short*)(ws + 70 * MB);
  float* sqq   = (float*)(ws + 78 * MB);            // 256KB
  float* sqk   = (float*)(ws + 78 * MB + 256 * 1024);
  short* Om = Amu;
  short* Os = Asg;

  cvt_bf16_k<<<2048, 256, 0, stream>>>(mu, Amu, MTOT * DMODEL / 8);
  cvt_bf16_k<<<2048, 256, 0, stream>>>(sigma, Asg, MTOT * DMODEL / 8);
  cvt_tr_k<<<dim3(96, 32), 256, 0, stream>>>(Wqm, Wqm_t, 1024, 3072);
  cvt_tr_k<<<dim3(96, 32), 256, 0, stream>>>(Wqs, Wqs_t, 1024, 3072);
  cvt_tr_k<<<dim3(32, 32), 256, 0, stream>>>(Wo, Wo_t, 1024, 1024);

  gemm128_k<<<dim3(32, 24), 256, 0, stream>>>(Amu, Wqm_t, bqm, 0, nullptr, Qm, Km, VmT);
  gemm128_k<<<dim3(32, 24), 256, 0, stream>>>(Asg, Wqs_t, bqs, 0, nullptr, Qs, Ks, VsT);

  norms_k<<<512, 256, 0, stream>>>(Qm, Qs, Km, Ks, sqq, sqk);

  attn_k<<<dim3(LSEQ / 128, BH), 512, 0, stream>>>(Qm, Km, VmT, Qs, Ks, VsT, sqq, sqk, Om, Os);

  // out-proj for mu and sigma as ONE GEMM (Om|Os contiguous, M=8192)
  gemm128_k<<<dim3(64, 8), 256, 0, stream>>>(Om, Wo_t, bo, 1, out, nullptr, nullptr, nullptr);
}

// Round 5
// 320.340 us; speedup vs baseline: 1.5898x; 1.5898x over previous
//
#include <hip/hip_runtime.h>
#include <hip/hip_bf16.h>

#define LSEQ   2048
#define DK     64
#define NH     16
#define BS     2
#define DMODEL 1024
#define BH     (BS*NH)    // 32
#define MTOT   (BS*LSEQ)  // 4096

typedef __attribute__((ext_vector_type(8))) short bf16x8;
typedef __attribute__((ext_vector_type(4))) float f32x4;

#define MFMA16(a,b,c) __builtin_amdgcn_mfma_f32_16x16x32_bf16((a),(b),(c),0,0,0)
#define GLD_LDS(g,l) __builtin_amdgcn_global_load_lds((const __attribute__((address_space(1))) void*)(g), (__attribute__((address_space(3))) void*)(l), 16, 0, 0)

__device__ __forceinline__ short f2bs(float f) {
  union { __hip_bfloat16 h; short s; } u; u.h = __float2bfloat16(f); return u.s;
}
__device__ __forceinline__ float b2f(unsigned short s) {
  union { unsigned u; float f; } v; v.u = ((unsigned)s) << 16; return v.f;
}
// cheap round-half-up bf16 (inputs guaranteed finite)
__device__ __forceinline__ unsigned short f2bs_c(float f) {
  union { float f; unsigned u; } v; v.f = f;
  return (unsigned short)((v.u + 0x8000u) >> 16);
}
__device__ __forceinline__ unsigned pk2c(float lo, float hi) {
  union { float f; unsigned u; } a, b; a.f = lo; b.f = hi;
  return ((a.u + 0x8000u) >> 16) | ((b.u + 0x8000u) & 0xffff0000u);
}
__device__ __forceinline__ unsigned pk2(float lo, float hi) {
  return (unsigned)(unsigned short)f2bs(lo) | (((unsigned)(unsigned short)f2bs(hi)) << 16);
}

// ---------------- f32 -> bf16 flat convert (vectorized) ----------------
__global__ __launch_bounds__(256) void cvt_bf16_k(const float* __restrict__ in,
                                                  short* __restrict__ out, int n8) {
  for (int i = blockIdx.x * blockDim.x + threadIdx.x; i < n8; i += gridDim.x * blockDim.x) {
    const float4* p = (const float4*)in + (size_t)i * 2;
    float4 a = p[0], b = p[1];
    uint4 o;
    o.x = pk2(a.x, a.y); o.y = pk2(a.z, a.w);
    o.z = pk2(b.x, b.y); o.w = pk2(b.z, b.w);
    ((uint4*)out)[i] = o;
  }
}

// ---------------- f32 [K][N] -> bf16 transposed [N][K] ----------------
__global__ __launch_bounds__(256) void cvt_tr_k(const float* __restrict__ W,
                                                short* __restrict__ Wt,
                                                int Krows, int Ncols) {
  __shared__ float tile[32][33];
  int n0 = blockIdx.x * 32, k0 = blockIdx.y * 32;
  int t = threadIdx.x;
#pragma unroll
  for (int i = 0; i < 4; ++i) {
    int idx = t + i * 256; int r = idx >> 5, c = idx & 31;
    tile[r][c] = W[(size_t)(k0 + r) * Ncols + n0 + c];
  }
  __syncthreads();
#pragma unroll
  for (int i = 0; i < 4; ++i) {
    int idx = t + i * 256; int r = idx >> 5, c = idx & 31;
    Wt[(size_t)(n0 + r) * Krows + k0 + c] = f2bs(tile[c][r]);
  }
}

// ---------------- 128x128-tile bf16 GEMM, K=1024 ----------------
__global__ __launch_bounds__(256) void gemm128_k(
    const short* __restrict__ A, const short* __restrict__ Bt,
    const float* __restrict__ bias, int mode,
    float* __restrict__ outF,
    short* __restrict__ Qb, short* __restrict__ Kb, short* __restrict__ VTb) {
  __shared__ short As[128 * 64];
  __shared__ short Bs[128 * 64];
  int tid = threadIdx.x, w = tid >> 6, ln = tid & 63, lg = ln >> 4, lr = ln & 15;
  int m0 = blockIdx.x * 128, n0 = blockIdx.y * 128;
  int wr = w >> 1, wc = w & 1;
  f32x4 acc[4][4] = {};

  for (int k0 = 0; k0 < 1024; k0 += 64) {
    __syncthreads();
#pragma unroll
    for (int i = 0; i < 4; ++i) {
      int cb = w * 64 + i * 256;
      int c = cb + ln;
      GLD_LDS(A  + (size_t)(m0 + (c >> 3)) * 1024 + k0 + (c & 7) * 8, &As[cb * 8]);
      GLD_LDS(Bt + (size_t)(n0 + (c >> 3)) * 1024 + k0 + (c & 7) * 8, &Bs[cb * 8]);
    }
    __syncthreads();
#pragma unroll
    for (int kh = 0; kh < 2; ++kh) {
      bf16x8 af[4], bfr[4];
#pragma unroll
      for (int mi = 0; mi < 4; ++mi)
        af[mi] = *(const bf16x8*)&As[(wr * 64 + mi * 16 + lr) * 64 + kh * 32 + lg * 8];
#pragma unroll
      for (int ni = 0; ni < 4; ++ni)
        bfr[ni] = *(const bf16x8*)&Bs[(wc * 64 + ni * 16 + lr) * 64 + kh * 32 + lg * 8];
#pragma unroll
      for (int mi = 0; mi < 4; ++mi)
#pragma unroll
        for (int ni = 0; ni < 4; ++ni)
          acc[mi][ni] = MFMA16(af[mi], bfr[ni], acc[mi][ni]);
    }
  }

#pragma unroll
  for (int ni = 0; ni < 4; ++ni) {
    int n = n0 + wc * 64 + ni * 16 + lr;
    float bv = bias[n];
    int part = n >> 10, cc = n & 1023, h = cc >> 6, dd = cc & 63;
#pragma unroll
    for (int mi = 0; mi < 4; ++mi) {
      int mbase = m0 + wr * 64 + mi * 16 + 4 * lg;
      float vv[4];
#pragma unroll
      for (int r = 0; r < 4; ++r) vv[r] = acc[mi][ni][r] + bv;
      if (mode == 1) {
#pragma unroll
        for (int r = 0; r < 4; ++r) outF[(size_t)(mbase + r) * 1024 + n] = vv[r];
      } else if (part == 2) {
        int b = mbase >> 11, tok = mbase & 2047, bh = b * NH + h;
        uint2 pk; pk.x = pk2c(vv[0], vv[1]); pk.y = pk2c(vv[2], vv[3]);
        *(uint2*)&VTb[((size_t)bh * DK + dd) * LSEQ + tok] = pk;
      } else {
        short* dst = (part == 0) ? Qb : Kb;
#pragma unroll
        for (int r = 0; r < 4; ++r) {
          int m = mbase + r;
          int b = m >> 11, tok = m & 2047, bh = b * NH + h;
          dst[((size_t)bh * LSEQ + tok) * DK + dd] = (short)f2bs_c(vv[r]);
        }
      }
    }
  }
}

// ---------------- per-row squared norms ----------------
__global__ __launch_bounds__(256) void norms_k(
    const short* __restrict__ Qm, const short* __restrict__ Qs,
    const short* __restrict__ Km, const short* __restrict__ Ks,
    float* __restrict__ sqq, float* __restrict__ sqk) {
  int id = blockIdx.x * 256 + threadIdx.x;  // 0..131071
  int row = id & 65535;
  const short* p1 = (id < 65536) ? Qm : Km;
  const short* p2 = (id < 65536) ? Qs : Ks;
  float* outp = (id < 65536) ? sqq : sqk;
  const uint4* a = (const uint4*)(p1 + (size_t)row * DK);
  const uint4* b = (const uint4*)(p2 + (size_t)row * DK);
  float s = 0.f;
#pragma unroll
  for (int i = 0; i < 8; ++i) {
    uint4 x = a[i], y = b[i];
    unsigned vx[4] = {x.x, x.y, x.z, x.w};
    unsigned vy[4] = {y.x, y.y, y.z, y.w};
#pragma unroll
    for (int j = 0; j < 4; ++j) {
      float l1 = b2f((unsigned short)(vx[j] & 0xffff)), h1 = b2f((unsigned short)(vx[j] >> 16));
      float l2 = b2f((unsigned short)(vy[j] & 0xffff)), h2 = b2f((unsigned short)(vy[j] >> 16));
      s += l1 * l1 + h1 * h1 + l2 * l2 + h2 * h2;
    }
  }
  outp[row] = s;
}

// ---------------- fused Wasserstein attention ----------------
// grid (L/128, BH); 512 threads = 8 waves; wave w owns 16 q-rows
// [q0+16w, q0+16w+16), full 64-k tiles (R2 structure: no spill).
// New vs R2: (1) P stays in registers -- swapped-QK output is permuted
// to the PV B-fragment layout with 16 ds_bpermute + cndmask selects
// (no P LDS round trip); (2) double-buffered K/V tiles, ONE barrier/tile.
__global__ __launch_bounds__(512, 4) void attn_k(
    const short* __restrict__ Qm, const short* __restrict__ Km, const short* __restrict__ VmT,
    const short* __restrict__ Qs, const short* __restrict__ Ks, const short* __restrict__ VsT,
    const float* __restrict__ sqq, const float* __restrict__ sqk,
    short* __restrict__ Om, short* __restrict__ Os) {
  int bh = blockIdx.y;
  int q0 = blockIdx.x * 128;
  int tid = threadIdx.x, w = tid >> 6, ln = tid & 63, lg = ln >> 4, lr = ln & 15;

  __shared__ __align__(16) short KmT[2][64][72];
  __shared__ __align__(16) short KsT[2][64][72];
  __shared__ __align__(16) short VtT[2][128][72];   // 73728 B total

  const size_t bhQ = (size_t)bh * LSEQ * DK;

  // Q fragments (MFMA B operand: col=lr=q, k=lg*8+j)
  bf16x8 qm0, qm1, qs0, qs1;
  {
    const short* qpm = Qm + bhQ + (size_t)(q0 + w * 16 + lr) * DK;
    const short* qps = Qs + bhQ + (size_t)(q0 + w * 16 + lr) * DK;
    qm0 = *(const bf16x8*)(qpm + lg * 8);
    qm1 = *(const bf16x8*)(qpm + 32 + lg * 8);
    qs0 = *(const bf16x8*)(qps + lg * 8);
    qs1 = *(const bf16x8*)(qps + 32 + lg * 8);
  }
  float sqQ = sqq[(size_t)bh * LSEQ + q0 + w * 16 + lr];
  const float* sqkp = sqk + (size_t)bh * LSEQ;

  // staging: 512 threads; 4 int4 each per tile (Km 1, Ks 1, Vm 1, Vs 1)
  int sr = tid >> 3, sc = tid & 7;
  const short* kmsrc  = Km  + bhQ + (size_t)sr * DK + sc * 8;
  const short* kssrc  = Ks  + bhQ + (size_t)sr * DK + sc * 8;
  const short* vm_src = VmT + ((size_t)bh * DK + sr) * LSEQ + sc * 8;
  const short* vs_src = VsT + ((size_t)bh * DK + sr) * LSEQ + sc * 8;

  // prolog: tile 0 -> buf0; tile 1 -> regs
  int4 rKm = *(const int4*)kmsrc;
  int4 rKs = *(const int4*)kssrc;
  int4 rV0 = *(const int4*)vm_src;
  int4 rV1 = *(const int4*)vs_src;
  *(int4*)&KmT[0][sr][sc * 8] = rKm;
  *(int4*)&KsT[0][sr][sc * 8] = rKs;
  *(int4*)&VtT[0][sr][sc * 8] = rV0;
  *(int4*)&VtT[0][sr + 64][sc * 8] = rV1;
  rKm = *(const int4*)(kmsrc + (size_t)64 * DK);
  rKs = *(const int4*)(kssrc + (size_t)64 * DK);
  rV0 = *(const int4*)(vm_src + 64);
  rV1 = *(const int4*)(vs_src + 64);
  __syncthreads();

  f32x4 acc[8] = {};
  float prs = 0.f;

  int srcA = ((ln & 16) ? 32 : 0) + lr;  // = ((lg&1)*2)*16 + lr
  int srcB = srcA + 16;
  bool hi = (ln >= 32);                  // = lg>>1

  const int NT = LSEQ / 64;
  for (int t = 0; t < NT; ++t) {
    int cur = t & 1, nxt = cur ^ 1;
    // write next tile (regs hold tile t+1); different buffer than compute
    if (t + 1 < NT) {
      *(int4*)&KmT[nxt][sr][sc * 8] = rKm;
      *(int4*)&KsT[nxt][sr][sc * 8] = rKs;
      *(int4*)&VtT[nxt][sr][sc * 8] = rV0;
      *(int4*)&VtT[nxt][sr + 64][sc * 8] = rV1;
    }
    // prefetch tile t+2 into regs (latency hidden under this tile's compute)
    if (t + 2 < NT) {
      int off = (t + 2) * 64;
      rKm = *(const int4*)(kmsrc + (size_t)off * DK);
      rKs = *(const int4*)(kssrc + (size_t)off * DK);
      rV0 = *(const int4*)(vm_src + off);
      rV1 = *(const int4*)(vs_src + off);
    }

    int k0 = t * 64;
    // QK^T (swapped): S[k][q]; lane (lg,lr): k=jt*16+4lg+r, q=lr
    uint2 pd0, pd1, pd2, pd3;
#pragma unroll
    for (int jt = 0; jt < 4; ++jt) {
      const short* kmr = &KmT[cur][jt * 16 + lr][0];
      const short* ksr = &KsT[cur][jt * 16 + lr][0];
      bf16x8 bm0 = *(const bf16x8*)(kmr + lg * 8);
      bf16x8 bm1 = *(const bf16x8*)(kmr + 32 + lg * 8);
      bf16x8 bs0 = *(const bf16x8*)(ksr + lg * 8);
      bf16x8 bs1 = *(const bf16x8*)(ksr + 32 + lg * 8);
      f32x4 s = {0.f, 0.f, 0.f, 0.f};
      s = MFMA16(bm0, qm0, s);
      s = MFMA16(bm1, qm1, s);
      s = MFMA16(bs0, qs0, s);
      s = MFMA16(bs1, qs1, s);
      f32x4 rsk = *(const f32x4*)&sqkp[k0 + jt * 16 + 4 * lg];
      float p[4];
#pragma unroll
      for (int r = 0; r < 4; ++r) {
        float w2 = fmaf(-2.f, s[r], rsk[r] + sqQ);
        float wd = sqrtf(fmaxf(w2, 0.f));
        float sim = __expf(-wd);
        p[r] = __expf(sim);
      }
      prs += (p[0] + p[1]) + (p[2] + p[3]);
      uint2 pk; pk.x = pk2c(p[0], p[1]); pk.y = pk2c(p[2], p[3]);
      if (jt == 0) pd0 = pk; else if (jt == 1) pd1 = pk;
      else if (jt == 2) pd2 = pk; else pd3 = pk;
    }

    // permute P to PV B-frag layout: lane (lg,lr) needs k=kh*32+lg*8+{0..7},
    // source lane ((lg&1)*2 + (j2>>1))*16 + lr, register jt=kh*2+(lg>>1).
#pragma unroll
    for (int kh = 0; kh < 2; ++kh) {
      uint2 plo = kh ? pd2 : pd0;   // jt = kh*2
      uint2 phi = kh ? pd3 : pd1;   // jt = kh*2+1
      unsigned a0 = __shfl((int)plo.x, srcA), a1 = __shfl((int)plo.y, srcA);
      unsigned a2 = __shfl((int)plo.x, srcB), a3 = __shfl((int)plo.y, srcB);
      unsigned b0 = __shfl((int)phi.x, srcA), b1 = __shfl((int)phi.y, srcA);
      unsigned b2 = __shfl((int)phi.x, srcB), b3 = __shfl((int)phi.y, srcB);
      union { uint4 u; bf16x8 v; } pw;
      pw.u.x = hi ? b0 : a0;
      pw.u.y = hi ? b1 : a1;
      pw.u.z = hi ? b2 : a2;
      pw.u.w = hi ? b3 : a3;
#pragma unroll
      for (int vt = 0; vt < 8; ++vt) {
        bf16x8 vb = *(const bf16x8*)&VtT[cur][vt * 16 + lr][kh * 32 + lg * 8];
        acc[vt] = MFMA16(vb, pw.v, acc[vt]);
      }
    }
    __syncthreads();   // next tile's writes target buf we just read
  }

  // rowsum: prs holds partial for q=lr over this lane's k's; reduce over lg
  {
    float v = prs;
    v += __shfl_xor(v, 16);
    v += __shfl_xor(v, 32);
    prs = v;
  }
  float inv = 1.f / prs;

  int b = bh >> 4, h = bh & 15;
  int tok = q0 + w * 16 + lr;
  size_t orow = ((size_t)(b * LSEQ + tok)) * DMODEL + h * DK;
#pragma unroll
  for (int vt = 0; vt < 8; ++vt) {
    short* obuf = (vt < 4) ? Om : Os;
    int vd = (vt & 3) * 16 + 4 * lg;
    float a0 = acc[vt][0] * inv, a1 = acc[vt][1] * inv;
    float a2 = acc[vt][2] * inv, a3 = acc[vt][3] * inv;
    uint2 pk; pk.x = pk2c(a0, a1); pk.y = pk2c(a2, a3);
    *(uint2*)(obuf + orow + vd) = pk;
  }
}

extern "C" void kernel_launch(void* const* d_in, const int* in_sizes, int n_in,
                              void* d_out, int out_size, void* d_ws, size_t ws_size,
                              hipStream_t stream) {
  const float* mu    = (const float*)d_in[0];
  const float* sigma = (const float*)d_in[1];
  const float* Wqm   = (const float*)d_in[2];
  const float* bqm   = (const float*)d_in[3];
  const float* Wqs   = (const float*)d_in[4];
  const float* bqs   = (const float*)d_in[5];
  const float* Wo    = (const float*)d_in[6];
  const float* bo    = (const float*)d_in[7];
  float* out = (float*)d_out;
  char* ws = (char*)d_ws;
  const size_t MB = 1u << 20;

  short* Amu   = (short*)(ws + 0);        // 8MB, reused as Om
  short* Asg   = (short*)(ws + 8 * MB);   // 8MB, reused as Os (contiguous with Om)
  short* Wqm_t = (short*)(ws + 16 * MB);  // 6MB
  short* Wqs_t = (short*)(ws + 22 * MB);  // 6MB
  short* Wo_t  = (short*)(ws + 28 * MB);  // 2MB
  short* Qm    = (short*)(ws + 30 * MB);  // 8MB each below
  short* Km    = (short*)(ws + 38 * MB);
  short* VmT   = (short*)(ws + 46 * MB);
  short* Qs    = (short*)(ws + 54 * MB);
  short* Ks    = (short*)(ws + 62 * MB);
  short* VsT   = (short*)(ws + 70 * MB);
  float* sqq   = (float*)(ws + 78 * MB);            // 256KB
  float* sqk   = (float*)(ws + 78 * MB + 256 * 1024);
  short* Om = Amu;
  short* Os = Asg;

  cvt_bf16_k<<<2048, 256, 0, stream>>>(mu, Amu, MTOT * DMODEL / 8);
  cvt_bf16_k<<<2048, 256, 0, stream>>>(sigma, Asg, MTOT * DMODEL / 8);
  cvt_tr_k<<<dim3(96, 32), 256, 0, stream>>>(Wqm, Wqm_t, 1024, 3072);
  cvt_tr_k<<<dim3(96, 32), 256, 0, stream>>>(Wqs, Wqs_t, 1024, 3072);
  cvt_tr_k<<<dim3(32, 32), 256, 0, stream>>>(Wo, Wo_t, 1024, 1024);

  gemm128_k<<<dim3(32, 24), 256, 0, stream>>>(Amu, Wqm_t, bqm, 0, nullptr, Qm, Km, VmT);
  gemm128_k<<<dim3(32, 24), 256, 0, stream>>>(Asg, Wqs_t, bqs, 0, nullptr, Qs, Ks, VsT);

  norms_k<<<512, 256, 0, stream>>>(Qm, Qs, Km, Ks, sqq, sqk);

  attn_k<<<dim3(LSEQ / 128, BH), 512, 0, stream>>>(Qm, Km, VmT, Qs, Ks, VsT, sqq, sqk, Om, Os);

  // out-proj for mu and sigma as ONE GEMM (Om|Os contiguous, M=8192)
  gemm128_k<<<dim3(64, 8), 256, 0, stream>>>(Om, Wo_t, bo, 1, out, nullptr, nullptr, nullptr);
}

// Round 6
// 287.360 us; speedup vs baseline: 1.7723x; 1.1148x over previous
//
#include <hip/hip_runtime.h>
#include <hip/hip_bf16.h>

#define LSEQ   2048
#define DK     64
#define NH     16
#define BS     2
#define DMODEL 1024
#define BH     (BS*NH)    // 32
#define MTOT   (BS*LSEQ)  // 4096

typedef __attribute__((ext_vector_type(8))) short bf16x8;
typedef __attribute__((ext_vector_type(4))) float f32x4;

#define MFMA16(a,b,c) __builtin_amdgcn_mfma_f32_16x16x32_bf16((a),(b),(c),0,0,0)
#define GLD_LDS(g,l) __builtin_amdgcn_global_load_lds((const __attribute__((address_space(1))) void*)(g), (__attribute__((address_space(3))) void*)(l), 16, 0, 0)

__device__ __forceinline__ short f2bs(float f) {
  union { __hip_bfloat16 h; short s; } u; u.h = __float2bfloat16(f); return u.s;
}
__device__ __forceinline__ float b2f(unsigned short s) {
  union { unsigned u; float f; } v; v.u = ((unsigned)s) << 16; return v.f;
}
// cheap round-half-up bf16 (inputs guaranteed finite)
__device__ __forceinline__ unsigned short f2bs_c(float f) {
  union { float f; unsigned u; } v; v.f = f;
  return (unsigned short)((v.u + 0x8000u) >> 16);
}
__device__ __forceinline__ unsigned pk2c(float lo, float hi) {
  union { float f; unsigned u; } a, b; a.f = lo; b.f = hi;
  return ((a.u + 0x8000u) >> 16) | ((b.u + 0x8000u) & 0xffff0000u);
}
__device__ __forceinline__ unsigned pk2(float lo, float hi) {
  return (unsigned)(unsigned short)f2bs(lo) | (((unsigned)(unsigned short)f2bs(hi)) << 16);
}

// ---------------- f32 -> bf16 flat convert (vectorized) ----------------
__global__ __launch_bounds__(256) void cvt_bf16_k(const float* __restrict__ in,
                                                  short* __restrict__ out, int n8) {
  for (int i = blockIdx.x * blockDim.x + threadIdx.x; i < n8; i += gridDim.x * blockDim.x) {
    const float4* p = (const float4*)in + (size_t)i * 2;
    float4 a = p[0], b = p[1];
    uint4 o;
    o.x = pk2(a.x, a.y); o.y = pk2(a.z, a.w);
    o.z = pk2(b.x, b.y); o.w = pk2(b.z, b.w);
    ((uint4*)out)[i] = o;
  }
}

// ---------------- f32 [K][N] -> bf16 transposed [N][K] ----------------
__global__ __launch_bounds__(256) void cvt_tr_k(const float* __restrict__ W,
                                                short* __restrict__ Wt,
                                                int Krows, int Ncols) {
  __shared__ float tile[32][33];
  int n0 = blockIdx.x * 32, k0 = blockIdx.y * 32;
  int t = threadIdx.x;
#pragma unroll
  for (int i = 0; i < 4; ++i) {
    int idx = t + i * 256; int r = idx >> 5, c = idx & 31;
    tile[r][c] = W[(size_t)(k0 + r) * Ncols + n0 + c];
  }
  __syncthreads();
#pragma unroll
  for (int i = 0; i < 4; ++i) {
    int idx = t + i * 256; int r = idx >> 5, c = idx & 31;
    Wt[(size_t)(n0 + r) * Krows + k0 + c] = f2bs(tile[c][r]);
  }
}

// ---------------- 128x128-tile bf16 GEMM, K=1024 ----------------
__global__ __launch_bounds__(256) void gemm128_k(
    const short* __restrict__ A, const short* __restrict__ Bt,
    const float* __restrict__ bias, int mode,
    float* __restrict__ outF,
    short* __restrict__ Qb, short* __restrict__ Kb, short* __restrict__ VTb) {
  __shared__ short As[128 * 64];
  __shared__ short Bs[128 * 64];
  int tid = threadIdx.x, w = tid >> 6, ln = tid & 63, lg = ln >> 4, lr = ln & 15;
  int m0 = blockIdx.x * 128, n0 = blockIdx.y * 128;
  int wr = w >> 1, wc = w & 1;
  f32x4 acc[4][4] = {};

  for (int k0 = 0; k0 < 1024; k0 += 64) {
    __syncthreads();
#pragma unroll
    for (int i = 0; i < 4; ++i) {
      int cb = w * 64 + i * 256;
      int c = cb + ln;
      GLD_LDS(A  + (size_t)(m0 + (c >> 3)) * 1024 + k0 + (c & 7) * 8, &As[cb * 8]);
      GLD_LDS(Bt + (size_t)(n0 + (c >> 3)) * 1024 + k0 + (c & 7) * 8, &Bs[cb * 8]);
    }
    __syncthreads();
#pragma unroll
    for (int kh = 0; kh < 2; ++kh) {
      bf16x8 af[4], bfr[4];
#pragma unroll
      for (int mi = 0; mi < 4; ++mi)
        af[mi] = *(const bf16x8*)&As[(wr * 64 + mi * 16 + lr) * 64 + kh * 32 + lg * 8];
#pragma unroll
      for (int ni = 0; ni < 4; ++ni)
        bfr[ni] = *(const bf16x8*)&Bs[(wc * 64 + ni * 16 + lr) * 64 + kh * 32 + lg * 8];
#pragma unroll
      for (int mi = 0; mi < 4; ++mi)
#pragma unroll
        for (int ni = 0; ni < 4; ++ni)
          acc[mi][ni] = MFMA16(af[mi], bfr[ni], acc[mi][ni]);
    }
  }

#pragma unroll
  for (int ni = 0; ni < 4; ++ni) {
    int n = n0 + wc * 64 + ni * 16 + lr;
    float bv = bias[n];
    int part = n >> 10, cc = n & 1023, h = cc >> 6, dd = cc & 63;
#pragma unroll
    for (int mi = 0; mi < 4; ++mi) {
      int mbase = m0 + wr * 64 + mi * 16 + 4 * lg;
      float vv[4];
#pragma unroll
      for (int r = 0; r < 4; ++r) vv[r] = acc[mi][ni][r] + bv;
      if (mode == 1) {
#pragma unroll
        for (int r = 0; r < 4; ++r) outF[(size_t)(mbase + r) * 1024 + n] = vv[r];
      } else if (part == 2) {
        int b = mbase >> 11, tok = mbase & 2047, bh = b * NH + h;
        uint2 pk; pk.x = pk2c(vv[0], vv[1]); pk.y = pk2c(vv[2], vv[3]);
        *(uint2*)&VTb[((size_t)bh * DK + dd) * LSEQ + tok] = pk;
      } else {
        short* dst = (part == 0) ? Qb : Kb;
#pragma unroll
        for (int r = 0; r < 4; ++r) {
          int m = mbase + r;
          int b = m >> 11, tok = m & 2047, bh = b * NH + h;
          dst[((size_t)bh * LSEQ + tok) * DK + dd] = (short)f2bs_c(vv[r]);
        }
      }
    }
  }
}

// ---------------- per-row squared norms ----------------
__global__ __launch_bounds__(256) void norms_k(
    const short* __restrict__ Qm, const short* __restrict__ Qs,
    const short* __restrict__ Km, const short* __restrict__ Ks,
    float* __restrict__ sqq, float* __restrict__ sqk) {
  int id = blockIdx.x * 256 + threadIdx.x;  // 0..131071
  int row = id & 65535;
  const short* p1 = (id < 65536) ? Qm : Km;
  const short* p2 = (id < 65536) ? Qs : Ks;
  float* outp = (id < 65536) ? sqq : sqk;
  const uint4* a = (const uint4*)(p1 + (size_t)row * DK);
  const uint4* b = (const uint4*)(p2 + (size_t)row * DK);
  float s = 0.f;
#pragma unroll
  for (int i = 0; i < 8; ++i) {
    uint4 x = a[i], y = b[i];
    unsigned vx[4] = {x.x, x.y, x.z, x.w};
    unsigned vy[4] = {y.x, y.y, y.z, y.w};
#pragma unroll
    for (int j = 0; j < 4; ++j) {
      float l1 = b2f((unsigned short)(vx[j] & 0xffff)), h1 = b2f((unsigned short)(vx[j] >> 16));
      float l2 = b2f((unsigned short)(vy[j] & 0xffff)), h2 = b2f((unsigned short)(vy[j] >> 16));
      s += l1 * l1 + h1 * h1 + l2 * l2 + h2 * h2;
    }
  }
  outp[row] = s;
}

// ---------------- fused Wasserstein attention ----------------
// grid (L/64, BH); 512 threads = 8 waves. BQ=64 -> 1024 blocks.
// Wave w = (qg = w&3, ks = w>>2): 16 q-rows [q0+16*qg, +16), k-half
// [ks*32, ks*32+32) of each 64-k tile. Register state identical to the
// R2 structure (acc[8] + prs, no duplication -> no spill); LDS 46 KB ->
// 3 blocks/CU co-resident with the 1024-block grid (~24 waves/CU).
// P via wave-private LDS columns (disjoint 32-col halves per ks).
// k-halves combined at kernel end through reused LDS scratch.
__global__ __launch_bounds__(512, 4) void attn_k(
    const short* __restrict__ Qm, const short* __restrict__ Km, const short* __restrict__ VmT,
    const short* __restrict__ Qs, const short* __restrict__ Ks, const short* __restrict__ VsT,
    const float* __restrict__ sqq, const float* __restrict__ sqk,
    short* __restrict__ Om, short* __restrict__ Os) {
  int bh = blockIdx.y;
  int q0 = blockIdx.x * 64;
  int tid = threadIdx.x, w = tid >> 6, ln = tid & 63, lg = ln >> 4, lr = ln & 15;
  int qg = w & 3, ks = w >> 2;

  __shared__ __align__(16) char pool[46080];
  short* KmT = (short*)pool;              // [64][72]
  short* KsT = (short*)(pool + 9216);     // [64][72]
  short* VtT = (short*)(pool + 18432);    // [128][72]
  short* P_t = (short*)(pool + 36864);    // [4 qg][16 q][72 k]

  const size_t bhQ = (size_t)bh * LSEQ * DK;

  // Q fragments (MFMA B operand: col=lr=q, k=lg*8+j)
  bf16x8 qm0, qm1, qs0, qs1;
  {
    const short* qpm = Qm + bhQ + (size_t)(q0 + qg * 16 + lr) * DK;
    const short* qps = Qs + bhQ + (size_t)(q0 + qg * 16 + lr) * DK;
    qm0 = *(const bf16x8*)(qpm + lg * 8);
    qm1 = *(const bf16x8*)(qpm + 32 + lg * 8);
    qs0 = *(const bf16x8*)(qps + lg * 8);
    qs1 = *(const bf16x8*)(qps + 32 + lg * 8);
  }
  float sqQ = sqq[(size_t)bh * LSEQ + q0 + qg * 16 + lr];
  const float* sqkp = sqk + (size_t)bh * LSEQ;

  // staging: 512 threads; 4 int4 each per tile (Km 1, Ks 1, Vm 1, Vs 1)
  int sr = tid >> 3, sc = tid & 7;
  const short* kmsrc  = Km  + bhQ + (size_t)sr * DK + sc * 8;
  const short* kssrc  = Ks  + bhQ + (size_t)sr * DK + sc * 8;
  const short* vm_src = VmT + ((size_t)bh * DK + sr) * LSEQ + sc * 8;
  const short* vs_src = VsT + ((size_t)bh * DK + sr) * LSEQ + sc * 8;

  int4 rKm = *(const int4*)kmsrc;
  int4 rKs = *(const int4*)kssrc;
  int4 rV0 = *(const int4*)vm_src;
  int4 rV1 = *(const int4*)vs_src;

  f32x4 acc[8] = {};
  float prs = 0.f;

  const int NT = LSEQ / 64;
  for (int t = 0; t < NT; ++t) {
    int k0 = t * 64;
    __syncthreads();   // all reads of previous tile done
    *(int4*)&KmT[sr * 72 + sc * 8] = rKm;
    *(int4*)&KsT[sr * 72 + sc * 8] = rKs;
    *(int4*)&VtT[sr * 72 + sc * 8] = rV0;
    *(int4*)&VtT[(sr + 64) * 72 + sc * 8] = rV1;
    __syncthreads();   // staged tile visible

    // prefetch next tile into regs (latency hidden under this tile's compute)
    {
      int k0n = (t < NT - 1) ? (k0 + 64) : k0;
      rKm = *(const int4*)(kmsrc + (size_t)k0n * DK);
      rKs = *(const int4*)(kssrc + (size_t)k0n * DK);
      rV0 = *(const int4*)(vm_src + k0n);
      rV1 = *(const int4*)(vs_src + k0n);
    }

    // QK^T (swapped): S[k][q] for this wave's k-half (2 jt sub-tiles)
#pragma unroll
    for (int jj = 0; jj < 2; ++jj) {
      int jt = ks * 2 + jj;
      const short* kmr = &KmT[(jt * 16 + lr) * 72];
      const short* ksr = &KsT[(jt * 16 + lr) * 72];
      bf16x8 bm0 = *(const bf16x8*)(kmr + lg * 8);
      bf16x8 bm1 = *(const bf16x8*)(kmr + 32 + lg * 8);
      bf16x8 bs0 = *(const bf16x8*)(ksr + lg * 8);
      bf16x8 bs1 = *(const bf16x8*)(ksr + 32 + lg * 8);
      f32x4 s = {0.f, 0.f, 0.f, 0.f};
      s = MFMA16(bm0, qm0, s);
      s = MFMA16(bm1, qm1, s);
      s = MFMA16(bs0, qs0, s);
      s = MFMA16(bs1, qs1, s);
      f32x4 rsk = *(const f32x4*)&sqkp[k0 + jt * 16 + 4 * lg];
      float p[4];
#pragma unroll
      for (int r = 0; r < 4; ++r) {
        float w2 = fmaf(-2.f, s[r], rsk[r] + sqQ);
        float wd = __builtin_amdgcn_sqrtf(fmaxf(w2, 0.f));
        float sim = __expf(-wd);
        p[r] = __expf(sim);
      }
      prs += (p[0] + p[1]) + (p[2] + p[3]);
      uint2 pk; pk.x = pk2c(p[0], p[1]); pk.y = pk2c(p[2], p[3]);
      *(uint2*)&P_t[(qg * 16 + lr) * 72 + jt * 16 + 4 * lg] = pk;
    }

    // PV over this wave's k-half: O[v][q] += V·P
    {
      bf16x8 pa = *(const bf16x8*)&P_t[(qg * 16 + lr) * 72 + ks * 32 + lg * 8];
#pragma unroll
      for (int vt = 0; vt < 8; ++vt) {
        bf16x8 vb = *(const bf16x8*)&VtT[(vt * 16 + lr) * 72 + ks * 32 + lg * 8];
        acc[vt] = MFMA16(vb, pa, acc[vt]);
      }
    }
  }

  // reduce prs across lg groups (lanes sharing lr): partial over this k-half
  {
    float v = prs;
    v += __shfl_xor(v, 16);
    v += __shfl_xor(v, 32);
    prs = v;
  }

  // combine k-halves (ks=1 -> ks=0) through LDS scratch
  float* scr  = (float*)pool;             // [4 qg][8 vt][64 ln] f32x4 = 32 KB
  float* scrP = (float*)(pool + 32768);   // [4 qg][64 ln] f32 = 1 KB
  __syncthreads();   // last tile's LDS reads done before overwrite
  if (ks == 1) {
#pragma unroll
    for (int vt = 0; vt < 8; ++vt)
      *(f32x4*)&scr[(qg * 512 + vt * 64 + ln) * 4] = acc[vt];
    scrP[qg * 64 + ln] = prs;
  }
  __syncthreads();
  if (ks == 0) {
    float inv = 1.f / (prs + scrP[qg * 64 + ln]);
    int b = bh >> 4, h = bh & 15;
    int tok = q0 + qg * 16 + lr;
    size_t orow = ((size_t)(b * LSEQ + tok)) * DMODEL + h * DK;
#pragma unroll
    for (int vt = 0; vt < 8; ++vt) {
      f32x4 o = acc[vt] + *(const f32x4*)&scr[(qg * 512 + vt * 64 + ln) * 4];
      short* obuf = (vt < 4) ? Om : Os;
      int vd = (vt & 3) * 16 + 4 * lg;
      uint2 pk; pk.x = pk2c(o[0] * inv, o[1] * inv);
      pk.y = pk2c(o[2] * inv, o[3] * inv);
      *(uint2*)(obuf + orow + vd) = pk;
    }
  }
}

extern "C" void kernel_launch(void* const* d_in, const int* in_sizes, int n_in,
                              void* d_out, int out_size, void* d_ws, size_t ws_size,
                              hipStream_t stream) {
  const float* mu    = (const float*)d_in[0];
  const float* sigma = (const float*)d_in[1];
  const float* Wqm   = (const float*)d_in[2];
  const float* bqm   = (const float*)d_in[3];
  const float* Wqs   = (const float*)d_in[4];
  const float* bqs   = (const float*)d_in[5];
  const float* Wo    = (const float*)d_in[6];
  const float* bo    = (const float*)d_in[7];
  float* out = (float*)d_out;
  char* ws = (char*)d_ws;
  const size_t MB = 1u << 20;

  short* Amu   = (short*)(ws + 0);        // 8MB, reused as Om
  short* Asg   = (short*)(ws + 8 * MB);   // 8MB, reused as Os (contiguous with Om)
  short* Wqm_t = (short*)(ws + 16 * MB);  // 6MB
  short* Wqs_t = (short*)(ws + 22 * MB);  // 6MB
  short* Wo_t  = (short*)(ws + 28 * MB);  // 2MB
  short* Qm    = (short*)(ws + 30 * MB);  // 8MB each below
  short* Km    = (short*)(ws + 38 * MB);
  short* VmT   = (short*)(ws + 46 * MB);
  short* Qs    = (short*)(ws + 54 * MB);
  short* Ks    = (short*)(ws + 62 * MB);
  short* VsT   = (short*)(ws + 70 * MB);
  float* sqq   = (float*)(ws + 78 * MB);            // 256KB
  float* sqk   = (float*)(ws + 78 * MB + 256 * 1024);
  short* Om = Amu;
  short* Os = Asg;

  cvt_bf16_k<<<2048, 256, 0, stream>>>(mu, Amu, MTOT * DMODEL / 8);
  cvt_bf16_k<<<2048, 256, 0, stream>>>(sigma, Asg, MTOT * DMODEL / 8);
  cvt_tr_k<<<dim3(96, 32), 256, 0, stream>>>(Wqm, Wqm_t, 1024, 3072);
  cvt_tr_k<<<dim3(96, 32), 256, 0, stream>>>(Wqs, Wqs_t, 1024, 3072);
  cvt_tr_k<<<dim3(32, 32), 256, 0, stream>>>(Wo, Wo_t, 1024, 1024);

  gemm128_k<<<dim3(32, 24), 256, 0, stream>>>(Amu, Wqm_t, bqm, 0, nullptr, Qm, Km, VmT);
  gemm128_k<<<dim3(32, 24), 256, 0, stream>>>(Asg, Wqs_t, bqs, 0, nullptr, Qs, Ks, VsT);

  norms_k<<<512, 256, 0, stream>>>(Qm, Qs, Km, Ks, sqq, sqk);

  attn_k<<<dim3(LSEQ / 64, BH), 512, 0, stream>>>(Qm, Km, VmT, Qs, Ks, VsT, sqq, sqk, Om, Os);

  // out-proj for mu and sigma as ONE GEMM (Om|Os contiguous, M=8192)
  gemm128_k<<<dim3(64, 8), 256, 0, stream>>>(Om, Wo_t, bo, 1, out, nullptr, nullptr, nullptr);
}